// Round 6
// baseline (1199.815 us; speedup 1.0000x reference)
//
#include <hip/hip_runtime.h>
#include <hip/hip_bf16.h>

// Problem: B=16, S=4096, H=1024
//   energy = tanh(x @ W^T + b); scores = softmax(energy, axis=S); out = sum_S scores*x
// GEMM view: M = B*S = 65536, N = H = 1024, K = H = 1024, both operands K-contiguous.
#define Bsz  16
#define Sdim 4096
#define Hdim 1024
#define Mtot (Bsz * Sdim)   // 65536
#define Kdim Hdim
#define Ndim Hdim

// ---- primary tile geometry (256^2, BK=32, 8 waves, 2-slot ring, 2 blocks/CU) ----
#define BM2 256
#define BN2 256
#define MT2 (Mtot / BM2)    // 256
#define NT2 (Ndim / BN2)    // 4
#define NKT32 (Kdim / 32)   // 32 K-tiles

// ---- fallback geometry (R1/R2-proven 128^2) ----
#define BM 128
#define BN 128
#define BK 32
#define MT (Mtot / BM)      // 512
#define NT (Ndim / BN)      // 8
#define NKT (Kdim / BK)     // 32

typedef short s16x8 __attribute__((ext_vector_type(8)));
typedef float f32x4 __attribute__((ext_vector_type(4)));

__device__ __forceinline__ unsigned short f2bf(float f) {
  __hip_bfloat16 h = __float2bfloat16(f);
  unsigned short u;
  __builtin_memcpy(&u, &h, 2);
  return u;
}
__device__ __forceinline__ float bf2f(unsigned short u) {
  __hip_bfloat16 h;
  __builtin_memcpy(&h, &u, 2);
  return __bfloat162float(h);
}
__device__ __forceinline__ s16x8 cvt8(float4 u, float4 v) {
  s16x8 r;
  r[0] = (short)f2bf(u.x); r[1] = (short)f2bf(u.y);
  r[2] = (short)f2bf(u.z); r[3] = (short)f2bf(u.w);
  r[4] = (short)f2bf(v.x); r[5] = (short)f2bf(v.y);
  r[6] = (short)f2bf(v.z); r[7] = (short)f2bf(v.w);
  return r;
}

// async global->LDS, 16B per lane; LDS dest is wave-uniform base + lane*16
__device__ __forceinline__ void gload_lds16(const unsigned short* g, unsigned short* l) {
  __builtin_amdgcn_global_load_lds(
      (const __attribute__((address_space(1))) unsigned int*)g,
      (__attribute__((address_space(3))) unsigned int*)l,
      16, 0, 0);
}

// ---- kernel 0: X fp32 [M][K] -> bf16 Xb (134 MB) ----
__global__ __launch_bounds__(256) void xconv_kernel(const float* __restrict__ X,
                                                    unsigned short* __restrict__ Xb) {
  size_t i = (size_t)blockIdx.x * 256 + threadIdx.x;  // 8 elements per thread
  float4 u = reinterpret_cast<const float4*>(X)[2 * i];
  float4 v = reinterpret_cast<const float4*>(X)[2 * i + 1];
  reinterpret_cast<s16x8*>(Xb)[i] = cvt8(u, v);
}

// ---- kernel 1: W fp32 [N][K] -> bf16 Wb (2 MB) ----
__global__ __launch_bounds__(256) void wconv_kernel(const float* __restrict__ W,
                                                    unsigned short* __restrict__ Wb) {
  int i = blockIdx.x * 256 + threadIdx.x;
  float4 v = reinterpret_cast<const float4*>(W)[i];
  ushort4 o;
  o.x = f2bf(v.x); o.y = f2bf(v.y); o.z = f2bf(v.z); o.w = f2bf(v.w);
  reinterpret_cast<ushort4*>(Wb)[i] = o;
}

// =====================================================================
// kernel 2 (primary): 256^2, BK=32, 2-slot ring, 68 KB LDS -> 2 blocks/CU.
//
// 512 threads = 8 waves (2 wm x 4 wn); per-wave output 128x64.
// Per K-tile(32): 2 phases x 16 MFMA (mh0 then mh1); B-frags read once in
// ph0 and register-cached for ph1 -> 12 ds_read_b128/wave/K-tile.
// Staging: both A(t+1) and B(t+1) (4 gload_lds) issued at ph0 of tile t;
// single vmcnt(0) at ph1 end (cover distance ~1400 cy > HBM latency; the
// co-resident second block fills any residual stall).
// Occupancy is the round's lever: 1 -> 2 blocks/CU so one block's
// barrier/lgkm/epilogue gaps are filled by the other block's MFMAs.
//
// Swizzle (R3/R5-proven, 0 bank conflicts): within a [256][32] subarray,
// logical (row, lk 16B-slot) stored at slot lk ^ ((row>>1)&3); inverse
// applied to the per-lane GLOBAL source column so the linear gload_lds
// dest lands data pre-swizzled (rule #21).
// =====================================================================
__global__ __launch_bounds__(512, 4) void attn_main(
    const unsigned short* __restrict__ Xb,  // [Mtot][Kdim] bf16
    const unsigned short* __restrict__ Wb,  // [Ndim][Kdim] bf16
    const float* __restrict__ bias,         // [Ndim]
    float* __restrict__ lpart,              // [MT2][Ndim]
    float* __restrict__ cpart) {            // [MT2][Ndim]
  __shared__ unsigned short Asl[2][BM2 * 32];  // 32 KB
  __shared__ unsigned short Bsl[2][BN2 * 32];  // 32 KB
  __shared__ float red[2][2][BN2];             // 4 KB  -> 68 KB total

  // XCD-chunked bijective swizzle (nwg=1024, 1024%8==0). Consecutive swz on
  // one XCD share mt -> the 4 nt-blocks sharing an A-panel co-reside on L2.
  int bid = blockIdx.x;
  int swz = (bid & 7) * (MT2 * NT2 / 8) + (bid >> 3);
  const int mt = swz >> 2;         // 0..255
  const int nt = swz & 3;          // 0..3
  const int m0 = mt * BM2;
  const int n0 = nt * BN2;

  const int tid  = threadIdx.x;
  const int l    = tid & 63;       // lane
  const int w    = tid >> 6;       // wave 0..7
  const int wm   = w >> 2;         // 0..1 (M half)
  const int wn   = w & 3;          // 0..3 (N quarter)
  const int lr   = l & 15;
  const int lk   = l >> 4;

  f32x4 acc[8][4];
#pragma unroll
  for (int i = 0; i < 8; i++)
#pragma unroll
    for (int j = 0; j < 4; j++) acc[i][j] = (f32x4){0.f, 0.f, 0.f, 0.f};

  // ---- staging source (inverse-swizzled global addresses) ----
  // gload unit = 512 thr x 16B = 8 KB = 128 rows x 32 cols. Wave w covers
  // rows [w*16, w*16+16); lane row += l>>2, src col slot = (l&3)^((l>>3)&3).
  const int srow = w * 16 + (l >> 2);
  const int scol = (((l & 3) ^ ((l >> 3) & 3)) << 3);  // elements
  const unsigned short* srcA0 = Xb + (size_t)(m0 + srow) * Kdim + scol;
  const unsigned short* srcB0 = Wb + (size_t)(n0 + srow) * Kdim + scol;

  // ---- fragment read offsets (swizzled, elements within [256][32] slot) ----
  int offA[2][4], offB[4];
#pragma unroll
  for (int mh = 0; mh < 2; mh++)
#pragma unroll
    for (int j = 0; j < 4; j++) {
      const int r = wm * 128 + mh * 64 + j * 16 + lr;
      offA[mh][j] = r * 32 + ((lk ^ ((r >> 1) & 3)) << 3);
    }
#pragma unroll
  for (int n = 0; n < 4; n++) {
    const int rn = wn * 64 + n * 16 + lr;
    offB[n] = rn * 32 + ((lk ^ ((rn >> 1) & 3)) << 3);
  }

  // stage a full 16 KB K-tile of A or B (2 gload_lds per thread)
#define STAGE_A(tp) do {                                                \
    unsigned short* d = &Asl[(tp) & 1][w * 512];                        \
    const unsigned short* g = srcA0 + (size_t)(tp) * 32;                \
    gload_lds16(g, d);                                                  \
    gload_lds16(g + (size_t)128 * Kdim, d + 4096);                      \
  } while (0)
#define STAGE_B(tp) do {                                                \
    unsigned short* d = &Bsl[(tp) & 1][w * 512];                        \
    const unsigned short* g = srcB0 + (size_t)(tp) * 32;                \
    gload_lds16(g, d);                                                  \
    gload_lds16(g + (size_t)128 * Kdim, d + 4096);                      \
  } while (0)

#define MID_BARRIER() do {                                   \
    asm volatile("" ::: "memory");                           \
    __builtin_amdgcn_s_barrier();                            \
    asm volatile("s_waitcnt lgkmcnt(0)" ::: "memory");       \
    __builtin_amdgcn_sched_barrier(0);                       \
  } while (0)
#define END_BARRIER() do {                                   \
    asm volatile("" ::: "memory");                           \
    __builtin_amdgcn_s_barrier();                            \
  } while (0)

  // ---- prologue: stage tile 0, land it ----
  STAGE_A(0); STAGE_B(0);
  asm volatile("s_waitcnt vmcnt(0)" ::: "memory");
  END_BARRIER();

  s16x8 bf[4];

  // ---- main loop: 32 K-tiles x 2 phases ----
  for (int t = 0; t < NKT32; ++t) {
    const int s = t & 1;
    const unsigned short* As = Asl[s];
    const unsigned short* Bs = Bsl[s];
    const bool more = (t + 1 < NKT32);
    s16x8 af[4];

    // ===== phase 0: mh0 + B read; stage tile t+1 =====
#pragma unroll
    for (int j = 0; j < 4; ++j) af[j] = *(const s16x8*)&As[offA[0][j]];
#pragma unroll
    for (int n = 0; n < 4; ++n) bf[n] = *(const s16x8*)&Bs[offB[n]];
    if (more) { STAGE_A(t + 1); STAGE_B(t + 1); }
    MID_BARRIER();
    __builtin_amdgcn_s_setprio(1);
#pragma unroll
    for (int j = 0; j < 4; ++j)
#pragma unroll
      for (int n = 0; n < 4; ++n)
        acc[j][n] = __builtin_amdgcn_mfma_f32_16x16x32_bf16(af[j], bf[n], acc[j][n], 0, 0, 0);
    __builtin_amdgcn_s_setprio(0);
    END_BARRIER();

    // ===== phase 1: mh1 (B register-cached) =====
#pragma unroll
    for (int j = 0; j < 4; ++j) af[j] = *(const s16x8*)&As[offA[1][j]];
    MID_BARRIER();
    __builtin_amdgcn_s_setprio(1);
#pragma unroll
    for (int j = 0; j < 4; ++j)
#pragma unroll
      for (int n = 0; n < 4; ++n)
        acc[4 + j][n] = __builtin_amdgcn_mfma_f32_16x16x32_bf16(af[j], bf[n], acc[4 + j][n], 0, 0, 0);
    __builtin_amdgcn_s_setprio(0);
    if (more) asm volatile("s_waitcnt vmcnt(0)" ::: "memory");  // t+1 resident
    END_BARRIER();
  }

  // ---- epilogue: e = tanh(acc+bias); l = sum exp(e), c = sum exp(e)*x ----
  // C/D layout: col = lane&15, row = (lane>>4)*4 + reg.
  // acc[m8] rows: wm*128 + (m8>>2)*64 + (m8&3)*16. tanh bounded -> no max sub.
  float lsum[4], csum[4];
#pragma unroll
  for (int nr = 0; nr < 4; nr++) {
    const int o = n0 + wn * 64 + nr * 16 + lr;
    const float bv = bias[o];
    float lacc = 0.f, cacc = 0.f;
#pragma unroll
    for (int m8 = 0; m8 < 8; m8++) {
      const int sr = m0 + wm * 128 + (m8 >> 2) * 64 + (m8 & 3) * 16 + lk * 4;
#pragma unroll
      for (int r = 0; r < 4; r++) {
        float e  = acc[m8][nr][r] + bv;
        float t  = __expf(2.f * e);
        float th = 1.f - __fdividef(2.f, t + 1.f);  // tanh(e)
        float sc = __expf(th);
        float xv = bf2f(Xb[(size_t)(sr + r) * Kdim + o]);  // L2-warm
        lacc += sc;
        cacc += sc * xv;
      }
    }
    lacc += __shfl_xor(lacc, 16); lacc += __shfl_xor(lacc, 32);
    cacc += __shfl_xor(cacc, 16); cacc += __shfl_xor(cacc, 32);
    lsum[nr] = lacc; csum[nr] = cacc;
  }

  if (lk == 0) {
#pragma unroll
    for (int nr = 0; nr < 4; nr++) {
      red[wm][0][wn * 64 + nr * 16 + lr] = lsum[nr];
      red[wm][1][wn * 64 + nr * 16 + lr] = csum[nr];
    }
  }
  __syncthreads();
  if (tid < BN2) {
    float L = red[0][0][tid] + red[1][0][tid];
    float C = red[0][1][tid] + red[1][1][tid];
    lpart[(size_t)mt * Ndim + n0 + tid] = L;
    cpart[(size_t)mt * Ndim + n0 + tid] = C;
  }
}

// ---- fallback main (R2-proven 128^2 reg-staged path, if ws too small) ----
__global__ __launch_bounds__(256) void attn_main_fb(
    const float* __restrict__ X, const unsigned short* __restrict__ Wb,
    const float* __restrict__ bias, float* __restrict__ lpart, float* __restrict__ cpart) {
  __shared__ unsigned short Al[BM * BK];
  __shared__ unsigned short Bl[BN * BK];
  __shared__ float red[2][2][BN];
  int bid = blockIdx.x;
  int swz = (bid & 7) * (MT * NT / 8) + (bid >> 3);
  int mt = swz >> 3, nt = swz & 7;
  const int m0 = mt * BM, n0 = nt * BN;
  const int tid = threadIdx.x, lane = tid & 63, wave = tid >> 6;
  const int wm = wave >> 1, wn = wave & 1, lr = lane & 15, lk = lane >> 4;
  f32x4 acc[4][4];
#pragma unroll
  for (int i = 0; i < 4; i++)
#pragma unroll
    for (int j = 0; j < 4; j++) acc[i][j] = (f32x4){0.f, 0.f, 0.f, 0.f};
  const int srow_st = tid >> 1, scol_st = (tid & 1) * 16;
  const float*          Ag = X  + (size_t)(m0 + srow_st) * Kdim + scol_st;
  const unsigned short* Bg = Wb + (size_t)(n0 + srow_st) * Kdim + scol_st;
  float4 a0 = *(const float4*)(Ag + 0), a1 = *(const float4*)(Ag + 4);
  float4 a2 = *(const float4*)(Ag + 8), a3 = *(const float4*)(Ag + 12);
  s16x8 b0 = *(const s16x8*)(Bg + 0), b1 = *(const s16x8*)(Bg + 8);
  for (int kt = 0; kt < NKT; ++kt) {
    __syncthreads();
    *(s16x8*)&Al[srow_st * BK + scol_st]     = cvt8(a0, a1);
    *(s16x8*)&Al[srow_st * BK + scol_st + 8] = cvt8(a2, a3);
    *(s16x8*)&Bl[srow_st * BK + scol_st]     = b0;
    *(s16x8*)&Bl[srow_st * BK + scol_st + 8] = b1;
    __syncthreads();
    if (kt + 1 < NKT) {
      const float* ap = Ag + (kt + 1) * BK;
      a0 = *(const float4*)(ap);     a1 = *(const float4*)(ap + 4);
      a2 = *(const float4*)(ap + 8); a3 = *(const float4*)(ap + 12);
      const unsigned short* bp = Bg + (kt + 1) * BK;
      b0 = *(const s16x8*)(bp);      b1 = *(const s16x8*)(bp + 8);
    }
    s16x8 af[4], bfr[4];
#pragma unroll
    for (int mr = 0; mr < 4; mr++)
      af[mr] = *(const s16x8*)&Al[(wm * 64 + mr * 16 + lr) * BK + lk * 8];
#pragma unroll
    for (int nr = 0; nr < 4; nr++)
      bfr[nr] = *(const s16x8*)&Bl[(wn * 64 + nr * 16 + lr) * BK + lk * 8];
#pragma unroll
    for (int mr = 0; mr < 4; mr++)
#pragma unroll
      for (int nr = 0; nr < 4; nr++)
        acc[mr][nr] = __builtin_amdgcn_mfma_f32_16x16x32_bf16(af[mr], bfr[nr], acc[mr][nr], 0, 0, 0);
  }
  float lsum[4], csum[4];
#pragma unroll
  for (int nr = 0; nr < 4; nr++) {
    const int o = n0 + wn * 64 + nr * 16 + lr;
    const float bv = bias[o];
    float lacc = 0.f, cacc = 0.f;
#pragma unroll
    for (int mr = 0; mr < 4; mr++) {
      const int sr = m0 + wm * 64 + mr * 16 + lk * 4;
#pragma unroll
      for (int r = 0; r < 4; r++) {
        float e  = acc[mr][nr][r] + bv;
        float t  = __expf(2.f * e);
        float th = 1.f - __fdividef(2.f, t + 1.f);
        float sc = __expf(th);
        float xv = X[(size_t)(sr + r) * Kdim + o];
        lacc += sc; cacc += sc * xv;
      }
    }
    lacc += __shfl_xor(lacc, 16); lacc += __shfl_xor(lacc, 32);
    cacc += __shfl_xor(cacc, 16); cacc += __shfl_xor(cacc, 32);
    lsum[nr] = lacc; csum[nr] = cacc;
  }
  if (lk == 0) {
#pragma unroll
    for (int nr = 0; nr < 4; nr++) {
      red[wm][0][wn * 64 + nr * 16 + lr] = lsum[nr];
      red[wm][1][wn * 64 + nr * 16 + lr] = csum[nr];
    }
  }
  __syncthreads();
  if (tid < BN) {
    float L = red[0][0][tid] + red[1][0][tid];
    float C = red[0][1][tid] + red[1][1][tid];
    lpart[(size_t)mt * Ndim + n0 + tid] = L;
    cpart[(size_t)mt * Ndim + n0 + tid] = C;
  }
}

// ---- kernel 3: combine s-chunks -> out[b][o] ----
__global__ __launch_bounds__(256) void finalize_kernel(const float* __restrict__ lpart,
                                                       const float* __restrict__ cpart,
                                                       float* __restrict__ out, int chunks) {
  int i = blockIdx.x * 256 + threadIdx.x;
  int b = i >> 10, o = i & 1023;
  float L = 0.f, C = 0.f;
  for (int sc = 0; sc < chunks; ++sc) {
    size_t idx = (size_t)(b * chunks + sc) * Ndim + o;
    L += lpart[idx];
    C += cpart[idx];
  }
  out[i] = C / L;
}

extern "C" void kernel_launch(void* const* d_in, const int* in_sizes, int n_in,
                              void* d_out, int out_size, void* d_ws, size_t ws_size,
                              hipStream_t stream) {
  const float* X    = (const float*)d_in[0];
  const float* W    = (const float*)d_in[1];
  const float* bias = (const float*)d_in[2];
  float* out = (float*)d_out;

  const size_t xb_bytes = (size_t)Mtot * Kdim * 2;        // 134 MB
  const size_t wb_bytes = (size_t)Ndim * Kdim * 2;        // 2 MB
  const size_t lp_bytes = (size_t)MT * Ndim * 4;          // 2 MB (max of both paths)
  const size_t need = xb_bytes + wb_bytes + 2 * lp_bytes;

  if (ws_size >= need) {
    unsigned short* Xb = (unsigned short*)d_ws;
    unsigned short* Wb = (unsigned short*)((char*)d_ws + xb_bytes);
    float* lpart = (float*)((char*)d_ws + xb_bytes + wb_bytes);
    float* cpart = lpart + (size_t)MT2 * Ndim;
    xconv_kernel<<<dim3(Mtot * (Kdim / 8) / 256), dim3(256), 0, stream>>>(X, Xb);
    wconv_kernel<<<dim3(Ndim * Kdim / 1024), dim3(256), 0, stream>>>(W, Wb);
    attn_main<<<dim3(MT2 * NT2), dim3(512), 0, stream>>>(Xb, Wb, bias, lpart, cpart);
    finalize_kernel<<<dim3(Bsz * Hdim / 256), dim3(256), 0, stream>>>(lpart, cpart, out,
                                                                      Sdim / BM2);
  } else {
    unsigned short* Wb = (unsigned short*)d_ws;
    float* lpart = (float*)((char*)d_ws + wb_bytes);
    float* cpart = lpart + (size_t)MT * Ndim;
    wconv_kernel<<<dim3(Ndim * Kdim / 1024), dim3(256), 0, stream>>>(W, Wb);
    attn_main_fb<<<dim3(MT * NT), dim3(256), 0, stream>>>(X, Wb, bias, lpart, cpart);
    finalize_kernel<<<dim3(Bsz * Hdim / 256), dim3(256), 0, stream>>>(lpart, cpart, out,
                                                                      Sdim / BM);
  }
}

// Round 7
// 278.263 us; speedup vs baseline: 4.3118x; 4.3118x over previous
//
#include <hip/hip_runtime.h>
#include <hip/hip_bf16.h>

// Problem: B=16, S=4096, H=1024
//   energy = tanh(x @ W^T + b); scores = softmax(energy, axis=S); out = sum_S scores*x
// GEMM view: M = B*S = 65536, N = H = 1024, K = H = 1024.
#define Bsz  16
#define Sdim 4096
#define Hdim 1024
#define Mtot (Bsz * Sdim)   // 65536
#define Kdim Hdim
#define Ndim Hdim

// ---- primary tile geometry (256^2, BK=32, 8 waves 2Mx4N, 3-slot A ring) ----
#define BM2 256
#define BN2 256
#define MT2 (Mtot / BM2)    // 256
#define NT2 (Ndim / BN2)    // 4
#define NKT32 (Kdim / 32)   // 32 K-tiles

// ---- fallback geometry (R1/R2-proven 128^2) ----
#define BM 128
#define BN 128
#define BK 32
#define MT (Mtot / BM)      // 512
#define NT (Ndim / BN)      // 8
#define NKT (Kdim / BK)     // 32

typedef short s16x8 __attribute__((ext_vector_type(8)));
typedef float f32x4 __attribute__((ext_vector_type(4)));
typedef float f32x16 __attribute__((ext_vector_type(16)));

__device__ __forceinline__ unsigned short f2bf(float f) {
  __hip_bfloat16 h = __float2bfloat16(f);
  unsigned short u;
  __builtin_memcpy(&u, &h, 2);
  return u;
}
__device__ __forceinline__ float bf2f(unsigned short u) {
  __hip_bfloat16 h;
  __builtin_memcpy(&h, &u, 2);
  return __bfloat162float(h);
}
__device__ __forceinline__ s16x8 cvt8(float4 u, float4 v) {
  s16x8 r;
  r[0] = (short)f2bf(u.x); r[1] = (short)f2bf(u.y);
  r[2] = (short)f2bf(u.z); r[3] = (short)f2bf(u.w);
  r[4] = (short)f2bf(v.x); r[5] = (short)f2bf(v.y);
  r[6] = (short)f2bf(v.z); r[7] = (short)f2bf(v.w);
  return r;
}

// async global->LDS, 16B per lane; LDS dest is wave-uniform base + lane*16
__device__ __forceinline__ void gload_lds16(const unsigned short* g, unsigned short* l) {
  __builtin_amdgcn_global_load_lds(
      (const __attribute__((address_space(1))) unsigned int*)g,
      (__attribute__((address_space(3))) unsigned int*)l,
      16, 0, 0);
}

// ---- kernel 0: X fp32 [M][K] -> bf16 Xb (134 MB) ----
__global__ __launch_bounds__(256) void xconv_kernel(const float* __restrict__ X,
                                                    unsigned short* __restrict__ Xb) {
  size_t i = (size_t)blockIdx.x * 256 + threadIdx.x;
  float4 u = reinterpret_cast<const float4*>(X)[2 * i];
  float4 v = reinterpret_cast<const float4*>(X)[2 * i + 1];
  reinterpret_cast<s16x8*>(Xb)[i] = cvt8(u, v);
}

// ---- kernel 1 (primary): W fp32 [N][K] -> per-lane fragment-ordered bf16 pack.
// Wpack elem-index layout: (((ksg*32 + nblk)*64 + lane)*8 + j) holds
// W[nblk*32 + (lane&31)][ksg*16 + (lane>>5)*8 + j]  (B-operand of
// mfma_32x32x16: col = lane&31, k = (lane>>5)*8 + j). One s16x8 load per
// (ksg, nblk) per lane in the GEMM = fully coalesced, L2-resident.
__global__ __launch_bounds__(256) void wpack_kernel(const float* __restrict__ W,
                                                    unsigned short* __restrict__ Wp) {
  int i = blockIdx.x * 256 + threadIdx.x;   // 0 .. 64*32*64-1
  int l   = i & 63;
  int nb  = (i >> 6) & 31;
  int ksg = i >> 11;                        // 0..63
  int row = nb * 32 + (l & 31);
  int col = ksg * 16 + ((l >> 5) << 3);
  float4 u = *reinterpret_cast<const float4*>(&W[(size_t)row * Kdim + col]);
  float4 v = *reinterpret_cast<const float4*>(&W[(size_t)row * Kdim + col + 4]);
  reinterpret_cast<s16x8*>(Wp)[i] = cvt8(u, v);
}

// ---- kernel 1b (fallback path): W fp32 [N][K] -> row-major bf16 Wb ----
__global__ __launch_bounds__(256) void wconv_kernel(const float* __restrict__ W,
                                                    unsigned short* __restrict__ Wb) {
  int i = blockIdx.x * 256 + threadIdx.x;
  float4 v = reinterpret_cast<const float4*>(W)[i];
  ushort4 o;
  o.x = f2bf(v.x); o.y = f2bf(v.y); o.z = f2bf(v.z); o.w = f2bf(v.w);
  reinterpret_cast<ushort4*>(Wb)[i] = o;
}

// =====================================================================
// kernel 2 (primary): 256^2, BK=32, mfma_f32_32x32x16_bf16, A via LDS
// (3-slot ring, swizzled), B via coalesced L2 register loads (Wpack).
//
// 512 threads = 8 waves (2 wm x 4 wn); per-wave output 128x64 =
// 4 mi-blocks x 2 nj-blocks of 32x32; acc[4][2] f32x16 = 128 VGPR.
// Per K-tile(32): ph0 {4 A ds_reads (mi0,1), 4 B reg loads, stage A(t+2),
// MID, 8 MFMA}; ph1 {4 A ds_reads (mi2,3), MID, 8 MFMA, vmcnt(2), END}.
// LDS traffic: 8 b128/wave/K-tile (vs 24 in R5) — the LDS pipe was the
// measured floor; B is off-LDS entirely.
//
// vmcnt pool (per tile issues: B(t)x4 then A(t+2)x2): compiler's wait
// before ph0 MFMA retires B(t) and everything older (incl. A(t+1)) ->
// A(t+1) visible pre-END-barrier; end-of-tile vmcnt(2) (leave A(t+2))
// is the explicit guarantee. t=30: vmcnt(0); t=31: none.
//
// Swizzle (R3/R5-proven): within [256][32] slot, 16B-slot stored at
// slotIdx ^ ((row>>1)&3); inverse pre-applied to the per-lane GLOBAL
// source column so linear gload_lds dest lands data pre-swizzled.
// =====================================================================
__global__ __launch_bounds__(512, 2) void attn_main(
    const unsigned short* __restrict__ Xb,  // [Mtot][Kdim] bf16
    const unsigned short* __restrict__ Wp,  // packed B fragments
    const float* __restrict__ bias,         // [Ndim]
    float* __restrict__ lpart,              // [MT2][Ndim]
    float* __restrict__ cpart) {            // [MT2][Ndim]
  __shared__ unsigned short Asl[3][BM2 * 32];  // 48 KB
  __shared__ float red[2][2][BN2];             // 4 KB

  // XCD-chunked bijective swizzle (nwg=1024, 1024%8==0)
  int bid = blockIdx.x;
  int swz = (bid & 7) * (MT2 * NT2 / 8) + (bid >> 3);
  const int mt = swz >> 2;
  const int nt = swz & 3;
  const int m0 = mt * BM2;
  const int n0 = nt * BN2;

  const int tid  = threadIdx.x;
  const int l    = tid & 63;
  const int w    = tid >> 6;
  const int wm   = w >> 2;        // 0..1
  const int wn   = w & 3;         // 0..3
  const int lr31 = l & 31;
  const int hi   = l >> 5;        // 0..1

  f32x16 acc[4][2];
#pragma unroll
  for (int i = 0; i < 4; i++)
#pragma unroll
    for (int j = 0; j < 2; j++)
#pragma unroll
      for (int r = 0; r < 16; r++) acc[i][j][r] = 0.f;

  // ---- A staging source (inverse-swizzled global addresses) ----
  const int srow = w * 16 + (l >> 2);
  const int scol = (((l & 3) ^ ((l >> 3) & 3)) << 3);
  const unsigned short* srcA0 = Xb + (size_t)(m0 + srow) * Kdim + scol;

  // ---- A fragment read offsets (32x32 A-operand: row=lane&31, k=(lane>>5)*8+j) ----
  int offA[4][2];
#pragma unroll
  for (int mi = 0; mi < 4; mi++)
#pragma unroll
    for (int ks = 0; ks < 2; ks++) {
      const int r = wm * 128 + mi * 32 + lr31;
      offA[mi][ks] = r * 32 + (((ks * 2 + hi) ^ ((r >> 1) & 3)) << 3);
    }

  // ---- B fragment indices into Wpack ----
  const s16x8* bpack = (const s16x8*)Wp;
  const int nb0 = (n0 >> 5) + wn * 2;
  int nbl[2];
#pragma unroll
  for (int nj = 0; nj < 2; nj++) nbl[nj] = (nb0 + nj) * 64 + l;

#define STAGE_A3(slot, tp) do {                                         \
    unsigned short* d = &Asl[slot][w * 512];                            \
    const unsigned short* g = srcA0 + (size_t)(tp) * 32;                \
    gload_lds16(g, d);                                                  \
    gload_lds16(g + (size_t)128 * Kdim, d + 4096);                      \
  } while (0)

#define MID_BARRIER() do {                                   \
    asm volatile("" ::: "memory");                           \
    __builtin_amdgcn_s_barrier();                            \
    asm volatile("s_waitcnt lgkmcnt(0)" ::: "memory");       \
    __builtin_amdgcn_sched_barrier(0);                       \
  } while (0)
#define END_BARRIER() do {                                   \
    asm volatile("" ::: "memory");                           \
    __builtin_amdgcn_s_barrier();                            \
  } while (0)

  // ---- prologue: stage A(0)->slot0, A(1)->slot1; land A(0) ----
  STAGE_A3(0, 0);
  STAGE_A3(1, 1);
  asm volatile("s_waitcnt vmcnt(2)" ::: "memory");  // A(0) landed, A(1) flying
  END_BARRIER();

  int scur = 0;
  for (int t = 0; t < NKT32; ++t) {
    const unsigned short* As = Asl[scur];
    const int snn = (scur + 2 >= 3) ? scur - 1 : scur + 2;  // slot for t+2
    s16x8 af[2][2], bf[2][2];

    // ===== phase 0: mi 0,1 =====
#pragma unroll
    for (int mi = 0; mi < 2; ++mi)
#pragma unroll
      for (int ks = 0; ks < 2; ++ks)
        af[mi][ks] = *(const s16x8*)&As[offA[mi][ks]];
#pragma unroll
    for (int nj = 0; nj < 2; ++nj)
#pragma unroll
      for (int ks = 0; ks < 2; ++ks)
        bf[nj][ks] = bpack[(size_t)4096 * t + 2048 * ks + nbl[nj]];
    if (t < NKT32 - 2) STAGE_A3(snn, t + 2);
    MID_BARRIER();
    __builtin_amdgcn_s_setprio(1);
#pragma unroll
    for (int mi = 0; mi < 2; ++mi)
#pragma unroll
      for (int nj = 0; nj < 2; ++nj)
#pragma unroll
        for (int ks = 0; ks < 2; ++ks)
          acc[mi][nj] = __builtin_amdgcn_mfma_f32_32x32x16_bf16(af[mi][ks], bf[nj][ks], acc[mi][nj], 0, 0, 0);
    __builtin_amdgcn_s_setprio(0);
    END_BARRIER();

    // ===== phase 1: mi 2,3 =====
#pragma unroll
    for (int mi = 0; mi < 2; ++mi)
#pragma unroll
      for (int ks = 0; ks < 2; ++ks)
        af[mi][ks] = *(const s16x8*)&As[offA[2 + mi][ks]];
    MID_BARRIER();
    __builtin_amdgcn_s_setprio(1);
#pragma unroll
    for (int mi = 0; mi < 2; ++mi)
#pragma unroll
      for (int nj = 0; nj < 2; ++nj)
#pragma unroll
        for (int ks = 0; ks < 2; ++ks)
          acc[2 + mi][nj] = __builtin_amdgcn_mfma_f32_32x32x16_bf16(af[mi][ks], bf[nj][ks], acc[2 + mi][nj], 0, 0, 0);
    __builtin_amdgcn_s_setprio(0);
    if (t < NKT32 - 2)       asm volatile("s_waitcnt vmcnt(2)" ::: "memory");  // A(t+1) landed
    else if (t == NKT32 - 2) asm volatile("s_waitcnt vmcnt(0)" ::: "memory");
    END_BARRIER();
    scur = (scur == 2) ? 0 : scur + 1;
  }

  // ---- epilogue: e = tanh(acc+bias); l = sum exp(e), c = sum exp(e)*x ----
  // 32x32 C/D layout (verified m74/m101): col = lane&31,
  // row = (reg&3) + 8*(reg>>2) + 4*(lane>>5).
  // Lanes hi=0/hi=1 hold complementary rows -> one shfl_xor(32) per column.
  float lsum[2], csum[2];
#pragma unroll
  for (int nj = 0; nj < 2; nj++) {
    const int o = n0 + wn * 64 + nj * 32 + lr31;
    const float bv = bias[o];
    float lacc = 0.f, cacc = 0.f;
#pragma unroll
    for (int mi = 0; mi < 4; mi++) {
      const int rbase = m0 + wm * 128 + mi * 32 + 4 * hi;
#pragma unroll
      for (int r = 0; r < 16; r++) {
        const int sr = rbase + (r & 3) + 8 * (r >> 2);
        float e  = acc[mi][nj][r] + bv;
        float t  = __expf(2.f * e);
        float th = 1.f - __fdividef(2.f, t + 1.f);  // tanh(e); e bounded ~[-7,7]
        float sc = __expf(th);                      // in [0.37, 2.72] -> no max sub
        float xv = bf2f(Xb[(size_t)sr * Kdim + o]); // L2-warm
        lacc += sc;
        cacc += sc * xv;
      }
    }
    lacc += __shfl_xor(lacc, 32);
    cacc += __shfl_xor(cacc, 32);
    lsum[nj] = lacc; csum[nj] = cacc;
  }

  if (hi == 0) {
#pragma unroll
    for (int nj = 0; nj < 2; nj++) {
      red[wm][0][wn * 64 + nj * 32 + lr31] = lsum[nj];
      red[wm][1][wn * 64 + nj * 32 + lr31] = csum[nj];
    }
  }
  __syncthreads();
  if (tid < BN2) {
    float L = red[0][0][tid] + red[1][0][tid];
    float C = red[0][1][tid] + red[1][1][tid];
    lpart[(size_t)mt * Ndim + n0 + tid] = L;
    cpart[(size_t)mt * Ndim + n0 + tid] = C;
  }
}

// ---- fallback main (R2-proven 128^2 reg-staged path, if ws too small) ----
__global__ __launch_bounds__(256) void attn_main_fb(
    const float* __restrict__ X, const unsigned short* __restrict__ Wb,
    const float* __restrict__ bias, float* __restrict__ lpart, float* __restrict__ cpart) {
  __shared__ unsigned short Al[BM * BK];
  __shared__ unsigned short Bl[BN * BK];
  __shared__ float red[2][2][BN];
  int bid = blockIdx.x;
  int swz = (bid & 7) * (MT * NT / 8) + (bid >> 3);
  int mt = swz >> 3, nt = swz & 7;
  const int m0 = mt * BM, n0 = nt * BN;
  const int tid = threadIdx.x, lane = tid & 63, wave = tid >> 6;
  const int wm = wave >> 1, wn = wave & 1, lr = lane & 15, lk = lane >> 4;
  f32x4 acc[4][4];
#pragma unroll
  for (int i = 0; i < 4; i++)
#pragma unroll
    for (int j = 0; j < 4; j++) acc[i][j] = (f32x4){0.f, 0.f, 0.f, 0.f};
  const int srow_st = tid >> 1, scol_st = (tid & 1) * 16;
  const float*          Ag = X  + (size_t)(m0 + srow_st) * Kdim + scol_st;
  const unsigned short* Bg = Wb + (size_t)(n0 + srow_st) * Kdim + scol_st;
  float4 a0 = *(const float4*)(Ag + 0), a1 = *(const float4*)(Ag + 4);
  float4 a2 = *(const float4*)(Ag + 8), a3 = *(const float4*)(Ag + 12);
  s16x8 b0 = *(const s16x8*)(Bg + 0), b1 = *(const s16x8*)(Bg + 8);
  for (int kt = 0; kt < NKT; ++kt) {
    __syncthreads();
    *(s16x8*)&Al[srow_st * BK + scol_st]     = cvt8(a0, a1);
    *(s16x8*)&Al[srow_st * BK + scol_st + 8] = cvt8(a2, a3);
    *(s16x8*)&Bl[srow_st * BK + scol_st]     = b0;
    *(s16x8*)&Bl[srow_st * BK + scol_st + 8] = b1;
    __syncthreads();
    if (kt + 1 < NKT) {
      const float* ap = Ag + (kt + 1) * BK;
      a0 = *(const float4*)(ap);     a1 = *(const float4*)(ap + 4);
      a2 = *(const float4*)(ap + 8); a3 = *(const float4*)(ap + 12);
      const unsigned short* bp = Bg + (kt + 1) * BK;
      b0 = *(const s16x8*)(bp);      b1 = *(const s16x8*)(bp + 8);
    }
    s16x8 af[4], bfr[4];
#pragma unroll
    for (int mr = 0; mr < 4; mr++)
      af[mr] = *(const s16x8*)&Al[(wm * 64 + mr * 16 + lr) * BK + lk * 8];
#pragma unroll
    for (int nr = 0; nr < 4; nr++)
      bfr[nr] = *(const s16x8*)&Bl[(wn * 64 + nr * 16 + lr) * BK + lk * 8];
#pragma unroll
    for (int mr = 0; mr < 4; mr++)
#pragma unroll
      for (int nr = 0; nr < 4; nr++)
        acc[mr][nr] = __builtin_amdgcn_mfma_f32_16x16x32_bf16(af[mr], bfr[nr], acc[mr][nr], 0, 0, 0);
  }
  float lsum[4], csum[4];
#pragma unroll
  for (int nr = 0; nr < 4; nr++) {
    const int o = n0 + wn * 64 + nr * 16 + lr;
    const float bv = bias[o];
    float lacc = 0.f, cacc = 0.f;
#pragma unroll
    for (int mr = 0; mr < 4; mr++) {
      const int sr = m0 + wm * 64 + mr * 16 + lk * 4;
#pragma unroll
      for (int r = 0; r < 4; r++) {
        float e  = acc[mr][nr][r] + bv;
        float t  = __expf(2.f * e);
        float th = 1.f - __fdividef(2.f, t + 1.f);
        float sc = __expf(th);
        float xv = X[(size_t)(sr + r) * Kdim + o];
        lacc += sc; cacc += sc * xv;
      }
    }
    lacc += __shfl_xor(lacc, 16); lacc += __shfl_xor(lacc, 32);
    cacc += __shfl_xor(cacc, 16); cacc += __shfl_xor(cacc, 32);
    lsum[nr] = lacc; csum[nr] = cacc;
  }
  if (lk == 0) {
#pragma unroll
    for (int nr = 0; nr < 4; nr++) {
      red[wm][0][wn * 64 + nr * 16 + lr] = lsum[nr];
      red[wm][1][wn * 64 + nr * 16 + lr] = csum[nr];
    }
  }
  __syncthreads();
  if (tid < BN) {
    float L = red[0][0][tid] + red[1][0][tid];
    float C = red[0][1][tid] + red[1][1][tid];
    lpart[(size_t)mt * Ndim + n0 + tid] = L;
    cpart[(size_t)mt * Ndim + n0 + tid] = C;
  }
}

// ---- kernel 3: combine s-chunks -> out[b][o] ----
__global__ __launch_bounds__(256) void finalize_kernel(const float* __restrict__ lpart,
                                                       const float* __restrict__ cpart,
                                                       float* __restrict__ out, int chunks) {
  int i = blockIdx.x * 256 + threadIdx.x;
  int b = i >> 10, o = i & 1023;
  float L = 0.f, C = 0.f;
  for (int sc = 0; sc < chunks; ++sc) {
    size_t idx = (size_t)(b * chunks + sc) * Ndim + o;
    L += lpart[idx];
    C += cpart[idx];
  }
  out[i] = C / L;
}

extern "C" void kernel_launch(void* const* d_in, const int* in_sizes, int n_in,
                              void* d_out, int out_size, void* d_ws, size_t ws_size,
                              hipStream_t stream) {
  const float* X    = (const float*)d_in[0];
  const float* W    = (const float*)d_in[1];
  const float* bias = (const float*)d_in[2];
  float* out = (float*)d_out;

  const size_t xb_bytes = (size_t)Mtot * Kdim * 2;        // 134 MB
  const size_t wb_bytes = (size_t)Ndim * Kdim * 2;        // 2 MB
  const size_t lp_bytes = (size_t)MT * Ndim * 4;          // 2 MB
  const size_t need = xb_bytes + wb_bytes + 2 * lp_bytes;

  if (ws_size >= need) {
    unsigned short* Xb = (unsigned short*)d_ws;
    unsigned short* Wp = (unsigned short*)((char*)d_ws + xb_bytes);
    float* lpart = (float*)((char*)d_ws + xb_bytes + wb_bytes);
    float* cpart = lpart + (size_t)MT2 * Ndim;
    xconv_kernel<<<dim3(Mtot * (Kdim / 8) / 256), dim3(256), 0, stream>>>(X, Xb);
    wpack_kernel<<<dim3((Ndim / 32) * (Kdim / 16) * 64 / 256), dim3(256), 0, stream>>>(W, Wp);
    attn_main<<<dim3(MT2 * NT2), dim3(512), 0, stream>>>(Xb, Wp, bias, lpart, cpart);
    finalize_kernel<<<dim3(Bsz * Hdim / 256), dim3(256), 0, stream>>>(lpart, cpart, out,
                                                                      Sdim / BM2);
  } else {
    unsigned short* Wb = (unsigned short*)d_ws;
    float* lpart = (float*)((char*)d_ws + wb_bytes);
    float* cpart = lpart + (size_t)MT * Ndim;
    wconv_kernel<<<dim3(Ndim * Kdim / 1024), dim3(256), 0, stream>>>(W, Wb);
    attn_main_fb<<<dim3(MT * NT), dim3(256), 0, stream>>>(X, Wb, bias, lpart, cpart);
    finalize_kernel<<<dim3(Bsz * Hdim / 256), dim3(256), 0, stream>>>(lpart, cpart, out,
                                                                      Sdim / BM);
  }
}

// Round 8
// 251.462 us; speedup vs baseline: 4.7714x; 1.1066x over previous
//
#include <hip/hip_runtime.h>
#include <hip/hip_bf16.h>

// Problem: B=16, S=4096, H=1024
//   energy = tanh(x @ W^T + b); scores = softmax(energy, axis=S); out = sum_S scores*x
// GEMM view: M = B*S = 65536, N = H = 1024, K = H = 1024.
#define Bsz  16
#define Sdim 4096
#define Hdim 1024
#define Mtot (Bsz * Sdim)   // 65536
#define Kdim Hdim
#define Ndim Hdim

// ---- primary tile geometry (256^2, BK=32, 8 waves 2Mx4N, 4-slot A ring) ----
#define BM2 256
#define BN2 256
#define MT2 (Mtot / BM2)    // 256
#define NT2 (Ndim / BN2)    // 4
#define NKT32 (Kdim / 32)   // 32 K-tiles

// ---- fallback geometry (R1/R2-proven 128^2) ----
#define BM 128
#define BN 128
#define BK 32
#define MT (Mtot / BM)      // 512
#define NT (Ndim / BN)      // 8
#define NKT (Kdim / BK)     // 32

typedef short s16x8 __attribute__((ext_vector_type(8)));
typedef float f32x4 __attribute__((ext_vector_type(4)));

__device__ __forceinline__ unsigned short f2bf(float f) {
  __hip_bfloat16 h = __float2bfloat16(f);
  unsigned short u;
  __builtin_memcpy(&u, &h, 2);
  return u;
}
__device__ __forceinline__ float bf2f(unsigned short u) {
  __hip_bfloat16 h;
  __builtin_memcpy(&h, &u, 2);
  return __bfloat162float(h);
}
__device__ __forceinline__ s16x8 cvt8(float4 u, float4 v) {
  s16x8 r;
  r[0] = (short)f2bf(u.x); r[1] = (short)f2bf(u.y);
  r[2] = (short)f2bf(u.z); r[3] = (short)f2bf(u.w);
  r[4] = (short)f2bf(v.x); r[5] = (short)f2bf(v.y);
  r[6] = (short)f2bf(v.z); r[7] = (short)f2bf(v.w);
  return r;
}

// async global->LDS, 16B per lane; LDS dest is wave-uniform base + lane*16
__device__ __forceinline__ void gload_lds16(const unsigned short* g, unsigned short* l) {
  __builtin_amdgcn_global_load_lds(
      (const __attribute__((address_space(1))) unsigned int*)g,
      (__attribute__((address_space(3))) unsigned int*)l,
      16, 0, 0);
}

// ---- kernel 0: X fp32 [M][K] -> bf16 Xb (134 MB) ----
__global__ __launch_bounds__(256) void xconv_kernel(const float* __restrict__ X,
                                                    unsigned short* __restrict__ Xb) {
  size_t i = (size_t)blockIdx.x * 256 + threadIdx.x;
  float4 u = reinterpret_cast<const float4*>(X)[2 * i];
  float4 v = reinterpret_cast<const float4*>(X)[2 * i + 1];
  reinterpret_cast<s16x8*>(Xb)[i] = cvt8(u, v);
}

// ---- kernel 1 (primary): W fp32 [N][K] -> per-lane fragment pack for the
// B-operand of mfma_f32_16x16x32_bf16 (col = lane&15, k = (lane>>4)*8 + j).
// Wp16 frag layout: frag f = (t*64 + nb)*64 + lane holds
//   W[nb*16 + (lane&15)][t*32 + (lane>>4)*8 + j]   (8 bf16 per frag)
// so in the GEMM, bf[nr] = one fully-coalesced 16B load per lane (L2-hot).
__global__ __launch_bounds__(256) void wpack16_kernel(const float* __restrict__ W,
                                                      unsigned short* __restrict__ Wp) {
  int f = blockIdx.x * 256 + threadIdx.x;   // 0 .. 32*64*64-1
  int l  = f & 63;
  int nb = (f >> 6) & 63;
  int t  = f >> 12;                         // 0..31
  int row = nb * 16 + (l & 15);
  int col = t * 32 + ((l >> 4) << 3);
  float4 u = *reinterpret_cast<const float4*>(&W[(size_t)row * Kdim + col]);
  float4 v = *reinterpret_cast<const float4*>(&W[(size_t)row * Kdim + col + 4]);
  reinterpret_cast<s16x8*>(Wp)[f] = cvt8(u, v);
}

// ---- kernel 1b (fallback path): W fp32 [N][K] -> row-major bf16 Wb ----
__global__ __launch_bounds__(256) void wconv_kernel(const float* __restrict__ W,
                                                    unsigned short* __restrict__ Wb) {
  int i = blockIdx.x * 256 + threadIdx.x;
  float4 v = reinterpret_cast<const float4*>(W)[i];
  ushort4 o;
  o.x = f2bf(v.x); o.y = f2bf(v.y); o.z = f2bf(v.z); o.w = f2bf(v.w);
  reinterpret_cast<ushort4*>(Wb)[i] = o;
}

// =====================================================================
// kernel 2 (primary): 256^2, BK=32, mfma_f32_16x16x32_bf16.
// A via LDS (4-slot ring, R5's proven zero-conflict swizzle + read
// pattern), B via per-lane fragment loads from Wp16 (L2), double-buffered
// in registers across tiles (unroll-2, named bfA/bfB — rule #20).
//
// vmcnt invariant (NEVER drains in steady state — the R5/R7 stall fix):
// per tile t issue order: B(t+1)x4 (global) then A(t+3)x2 (gload_lds).
// One explicit s_waitcnt vmcnt(8) before ph0's MID barrier retires
// exactly {B(t), A(t+1)} and leaves {A(t+2), B(t+1), A(t+3)} = 8 flying.
// Tail: t=29 -> 6, t=30 -> 4, t=31 -> 0 (enumerated; stage stops at
// t=28, B-loads stop at t=30).
//
// Ring overwrite safety: stage A(t+3) -> slot (t-1)&3 issues after tile
// t-1's END barrier; every wave completed its slot-(t-1) ds_reads at its
// own lgkmcnt(0) before reaching that barrier.
// =====================================================================
__global__ __launch_bounds__(512, 2) void attn_main(
    const unsigned short* __restrict__ Xb,  // [Mtot][Kdim] bf16
    const unsigned short* __restrict__ Wp,  // packed B fragments (2 MB)
    const float* __restrict__ bias,         // [Ndim]
    float* __restrict__ lpart,              // [MT2][Ndim]
    float* __restrict__ cpart) {            // [MT2][Ndim]
  __shared__ unsigned short Asl[4][BM2 * 32];  // 64 KB
  __shared__ float red[2][2][BN2];             // 4 KB

  // XCD-chunked bijective swizzle (nwg=1024, 1024%8==0)
  int bid = blockIdx.x;
  int swz = (bid & 7) * (MT2 * NT2 / 8) + (bid >> 3);
  const int mt = swz >> 2;
  const int nt = swz & 3;
  const int m0 = mt * BM2;
  const int n0 = nt * BN2;

  const int tid  = threadIdx.x;
  const int l    = tid & 63;
  const int w    = tid >> 6;
  const int wm   = w >> 2;        // 0..1 (M half)
  const int wn   = w & 3;         // 0..3 (N quarter)
  const int lr   = l & 15;
  const int lk   = l >> 4;

  f32x4 acc[8][4];
#pragma unroll
  for (int i = 0; i < 8; i++)
#pragma unroll
    for (int j = 0; j < 4; j++) acc[i][j] = (f32x4){0.f, 0.f, 0.f, 0.f};

  // ---- A staging source (inverse-swizzled global addresses, R5-proven) ----
  const int srow = w * 16 + (l >> 2);
  const int scol = (((l & 3) ^ ((l >> 3) & 3)) << 3);
  const unsigned short* srcA0 = Xb + (size_t)(m0 + srow) * Kdim + scol;

  // ---- A fragment read offsets (R5-proven zero-conflict pattern) ----
  int offA[2][4];
#pragma unroll
  for (int mh = 0; mh < 2; mh++)
#pragma unroll
    for (int j = 0; j < 4; j++) {
      const int r = wm * 128 + mh * 64 + j * 16 + lr;
      offA[mh][j] = r * 32 + ((lk ^ ((r >> 1) & 3)) << 3);
    }

  // ---- B fragment base in Wp16 ----
  const s16x8* bp16 = (const s16x8*)Wp;
  const int nbB = nt * 16 + wn * 4;   // wave's four 16-col blocks

#define STAGE_A(tp) do {                                                \
    unsigned short* d = &Asl[(tp) & 3][w * 512];                        \
    const unsigned short* g = srcA0 + (size_t)(tp) * 32;                \
    gload_lds16(g, d);                                                  \
    gload_lds16(g + (size_t)128 * Kdim, d + 4096);                      \
  } while (0)

#define MID_BARRIER() do {                                   \
    asm volatile("" ::: "memory");                           \
    __builtin_amdgcn_s_barrier();                            \
    asm volatile("s_waitcnt lgkmcnt(0)" ::: "memory");       \
    __builtin_amdgcn_sched_barrier(0);                       \
  } while (0)
#define END_BARRIER() do {                                   \
    asm volatile("" ::: "memory");                           \
    __builtin_amdgcn_s_barrier();                            \
  } while (0)

  // One K32-tile: ph0 {4 A ds_reads, B(t+1) reg loads, stage A(t+3),
  // counted vmcnt, MID, 16 MFMA (mh0 x BFE)}, ph1 {4 A ds_reads, MID,
  // 16 MFMA (mh1 x BFE)}.
#define DO_TILE(T, BFE, BFO, LOADB, DOSTAGE, VMWAIT) do {                  \
    const unsigned short* As = Asl[(T) & 3];                               \
    s16x8 af[4];                                                           \
    _Pragma("unroll")                                                      \
    for (int j = 0; j < 4; ++j) af[j] = *(const s16x8*)&As[offA[0][j]];    \
    if (LOADB) {                                                           \
      _Pragma("unroll")                                                    \
      for (int nr = 0; nr < 4; ++nr)                                       \
        BFO[nr] = bp16[((size_t)((T) + 1) * 64 + nbB + nr) * 64 + l];      \
    }                                                                      \
    if (DOSTAGE) STAGE_A((T) + 3);                                         \
    VMWAIT;                                                                \
    MID_BARRIER();                                                         \
    __builtin_amdgcn_s_setprio(1);                                         \
    _Pragma("unroll")                                                      \
    for (int j = 0; j < 4; ++j)                                            \
      _Pragma("unroll")                                                    \
      for (int nr = 0; nr < 4; ++nr)                                       \
        acc[j][nr] = __builtin_amdgcn_mfma_f32_16x16x32_bf16(af[j], BFE[nr], acc[j][nr], 0, 0, 0); \
    __builtin_amdgcn_s_setprio(0);                                         \
    END_BARRIER();                                                         \
    _Pragma("unroll")                                                      \
    for (int j = 0; j < 4; ++j) af[j] = *(const s16x8*)&As[offA[1][j]];    \
    MID_BARRIER();                                                         \
    __builtin_amdgcn_s_setprio(1);                                         \
    _Pragma("unroll")                                                      \
    for (int j = 0; j < 4; ++j)                                            \
      _Pragma("unroll")                                                    \
      for (int nr = 0; nr < 4; ++nr)                                       \
        acc[4 + j][nr] = __builtin_amdgcn_mfma_f32_16x16x32_bf16(af[j], BFE[nr], acc[4 + j][nr], 0, 0, 0); \
    __builtin_amdgcn_s_setprio(0);                                         \
    END_BARRIER();                                                         \
  } while (0)

  s16x8 bfA[4], bfB[4];

  // ---- prologue: B(0) regs; stage A(0),A(1),A(2); land B(0)+A(0) ----
#pragma unroll
  for (int nr = 0; nr < 4; ++nr)
    bfA[nr] = bp16[((size_t)0 * 64 + nbB + nr) * 64 + l];
  STAGE_A(0); STAGE_A(1); STAGE_A(2);
  asm volatile("s_waitcnt vmcnt(4)" ::: "memory");  // retire B(0),A(0); A(1),A(2) fly
  END_BARRIER();

  // ---- main loop: 16 x 2 tiles (B double-buffer bfA/bfB) ----
  for (int i = 0; i < 16; ++i) {
    const int t0 = 2 * i;
    DO_TILE(t0, bfA, bfB, true, (i < 15),
            { if (i < 15) asm volatile("s_waitcnt vmcnt(8)" ::: "memory");
              else        asm volatile("s_waitcnt vmcnt(4)" ::: "memory"); });
    DO_TILE(t0 + 1, bfB, bfA, (i < 15), (i < 14),
            { if (i < 14)       asm volatile("s_waitcnt vmcnt(8)" ::: "memory");
              else if (i == 14) asm volatile("s_waitcnt vmcnt(6)" ::: "memory");
              else              asm volatile("s_waitcnt vmcnt(0)" ::: "memory"); });
  }

  // ---- epilogue (R5-proven): e = tanh(acc+bias); l=sum exp(e); c=sum exp(e)*x
  // C/D layout: col = lane&15, row = (lane>>4)*4 + reg.
  // acc[m8] rows: wm*128 + (m8>>2)*64 + (m8&3)*16. tanh bounded -> no max sub.
  float lsum[4], csum[4];
#pragma unroll
  for (int nr = 0; nr < 4; nr++) {
    const int o = n0 + wn * 64 + nr * 16 + lr;
    const float bv = bias[o];
    float lacc = 0.f, cacc = 0.f;
#pragma unroll
    for (int m8 = 0; m8 < 8; m8++) {
      const int sr = m0 + wm * 128 + (m8 >> 2) * 64 + (m8 & 3) * 16 + lk * 4;
#pragma unroll
      for (int r = 0; r < 4; r++) {
        float e  = acc[m8][nr][r] + bv;
        float t  = __expf(2.f * e);
        float th = 1.f - __fdividef(2.f, t + 1.f);  // tanh(e); e bounded ~[-7,7]
        float sc = __expf(th);                      // in [0.37, 2.72]
        float xv = bf2f(Xb[(size_t)(sr + r) * Kdim + o]);  // L2-warm
        lacc += sc;
        cacc += sc * xv;
      }
    }
    lacc += __shfl_xor(lacc, 16); lacc += __shfl_xor(lacc, 32);
    cacc += __shfl_xor(cacc, 16); cacc += __shfl_xor(cacc, 32);
    lsum[nr] = lacc; csum[nr] = cacc;
  }

  if (lk == 0) {
#pragma unroll
    for (int nr = 0; nr < 4; nr++) {
      red[wm][0][wn * 64 + nr * 16 + lr] = lsum[nr];
      red[wm][1][wn * 64 + nr * 16 + lr] = csum[nr];
    }
  }
  __syncthreads();
  if (tid < BN2) {
    float L = red[0][0][tid] + red[1][0][tid];
    float C = red[0][1][tid] + red[1][1][tid];
    lpart[(size_t)mt * Ndim + n0 + tid] = L;
    cpart[(size_t)mt * Ndim + n0 + tid] = C;
  }
}

// ---- fallback main (R2-proven 128^2 reg-staged path, if ws too small) ----
__global__ __launch_bounds__(256) void attn_main_fb(
    const float* __restrict__ X, const unsigned short* __restrict__ Wb,
    const float* __restrict__ bias, float* __restrict__ lpart, float* __restrict__ cpart) {
  __shared__ unsigned short Al[BM * BK];
  __shared__ unsigned short Bl[BN * BK];
  __shared__ float red[2][2][BN];
  int bid = blockIdx.x;
  int swz = (bid & 7) * (MT * NT / 8) + (bid >> 3);
  int mt = swz >> 3, nt = swz & 7;
  const int m0 = mt * BM, n0 = nt * BN;
  const int tid = threadIdx.x, lane = tid & 63, wave = tid >> 6;
  const int wm = wave >> 1, wn = wave & 1, lr = lane & 15, lk = lane >> 4;
  f32x4 acc[4][4];
#pragma unroll
  for (int i = 0; i < 4; i++)
#pragma unroll
    for (int j = 0; j < 4; j++) acc[i][j] = (f32x4){0.f, 0.f, 0.f, 0.f};
  const int srow_st = tid >> 1, scol_st = (tid & 1) * 16;
  const float*          Ag = X  + (size_t)(m0 + srow_st) * Kdim + scol_st;
  const unsigned short* Bg = Wb + (size_t)(n0 + srow_st) * Kdim + scol_st;
  float4 a0 = *(const float4*)(Ag + 0), a1 = *(const float4*)(Ag + 4);
  float4 a2 = *(const float4*)(Ag + 8), a3 = *(const float4*)(Ag + 12);
  s16x8 b0 = *(const s16x8*)(Bg + 0), b1 = *(const s16x8*)(Bg + 8);
  for (int kt = 0; kt < NKT; ++kt) {
    __syncthreads();
    *(s16x8*)&Al[srow_st * BK + scol_st]     = cvt8(a0, a1);
    *(s16x8*)&Al[srow_st * BK + scol_st + 8] = cvt8(a2, a3);
    *(s16x8*)&Bl[srow_st * BK + scol_st]     = b0;
    *(s16x8*)&Bl[srow_st * BK + scol_st + 8] = b1;
    __syncthreads();
    if (kt + 1 < NKT) {
      const float* ap = Ag + (kt + 1) * BK;
      a0 = *(const float4*)(ap);     a1 = *(const float4*)(ap + 4);
      a2 = *(const float4*)(ap + 8); a3 = *(const float4*)(ap + 12);
      const unsigned short* bp = Bg + (kt + 1) * BK;
      b0 = *(const s16x8*)(bp);      b1 = *(const s16x8*)(bp + 8);
    }
    s16x8 af[4], bfr[4];
#pragma unroll
    for (int mr = 0; mr < 4; mr++)
      af[mr] = *(const s16x8*)&Al[(wm * 64 + mr * 16 + lr) * BK + lk * 8];
#pragma unroll
    for (int nr = 0; nr < 4; nr++)
      bfr[nr] = *(const s16x8*)&Bl[(wn * 64 + nr * 16 + lr) * BK + lk * 8];
#pragma unroll
    for (int mr = 0; mr < 4; mr++)
#pragma unroll
      for (int nr = 0; nr < 4; nr++)
        acc[mr][nr] = __builtin_amdgcn_mfma_f32_16x16x32_bf16(af[mr], bfr[nr], acc[mr][nr], 0, 0, 0);
  }
  float lsum[4], csum[4];
#pragma unroll
  for (int nr = 0; nr < 4; nr++) {
    const int o = n0 + wn * 64 + nr * 16 + lr;
    const float bv = bias[o];
    float lacc = 0.f, cacc = 0.f;
#pragma unroll
    for (int mr = 0; mr < 4; mr++) {
      const int sr = m0 + wm * 64 + mr * 16 + lk * 4;
#pragma unroll
      for (int r = 0; r < 4; r++) {
        float e  = acc[mr][nr][r] + bv;
        float t  = __expf(2.f * e);
        float th = 1.f - __fdividef(2.f, t + 1.f);
        float sc = __expf(th);
        float xv = X[(size_t)(sr + r) * Kdim + o];
        lacc += sc; cacc += sc * xv;
      }
    }
    lacc += __shfl_xor(lacc, 16); lacc += __shfl_xor(lacc, 32);
    cacc += __shfl_xor(cacc, 16); cacc += __shfl_xor(cacc, 32);
    lsum[nr] = lacc; csum[nr] = cacc;
  }
  if (lk == 0) {
#pragma unroll
    for (int nr = 0; nr < 4; nr++) {
      red[wm][0][wn * 64 + nr * 16 + lr] = lsum[nr];
      red[wm][1][wn * 64 + nr * 16 + lr] = csum[nr];
    }
  }
  __syncthreads();
  if (tid < BN) {
    float L = red[0][0][tid] + red[1][0][tid];
    float C = red[0][1][tid] + red[1][1][tid];
    lpart[(size_t)mt * Ndim + n0 + tid] = L;
    cpart[(size_t)mt * Ndim + n0 + tid] = C;
  }
}

// ---- kernel 3: combine s-chunks -> out[b][o] ----
__global__ __launch_bounds__(256) void finalize_kernel(const float* __restrict__ lpart,
                                                       const float* __restrict__ cpart,
                                                       float* __restrict__ out, int chunks) {
  int i = blockIdx.x * 256 + threadIdx.x;
  int b = i >> 10, o = i & 1023;
  float L = 0.f, C = 0.f;
  for (int sc = 0; sc < chunks; ++sc) {
    size_t idx = (size_t)(b * chunks + sc) * Ndim + o;
    L += lpart[idx];
    C += cpart[idx];
  }
  out[i] = C / L;
}

extern "C" void kernel_launch(void* const* d_in, const int* in_sizes, int n_in,
                              void* d_out, int out_size, void* d_ws, size_t ws_size,
                              hipStream_t stream) {
  const float* X    = (const float*)d_in[0];
  const float* W    = (const float*)d_in[1];
  const float* bias = (const float*)d_in[2];
  float* out = (float*)d_out;

  const size_t xb_bytes = (size_t)Mtot * Kdim * 2;        // 134 MB
  const size_t wb_bytes = (size_t)Ndim * Kdim * 2;        // 2 MB
  const size_t lp_bytes = (size_t)MT * Ndim * 4;          // 2 MB
  const size_t need = xb_bytes + wb_bytes + 2 * lp_bytes;

  if (ws_size >= need) {
    unsigned short* Xb = (unsigned short*)d_ws;
    unsigned short* Wp = (unsigned short*)((char*)d_ws + xb_bytes);
    float* lpart = (float*)((char*)d_ws + xb_bytes + wb_bytes);
    float* cpart = lpart + (size_t)MT2 * Ndim;
    xconv_kernel<<<dim3(Mtot * (Kdim / 8) / 256), dim3(256), 0, stream>>>(X, Xb);
    wpack16_kernel<<<dim3(NKT32 * 64 * 64 / 256), dim3(256), 0, stream>>>(W, Wp);
    attn_main<<<dim3(MT2 * NT2), dim3(512), 0, stream>>>(Xb, Wp, bias, lpart, cpart);
    finalize_kernel<<<dim3(Bsz * Hdim / 256), dim3(256), 0, stream>>>(lpart, cpart, out,
                                                                      Sdim / BM2);
  } else {
    unsigned short* Wb = (unsigned short*)d_ws;
    float* lpart = (float*)((char*)d_ws + wb_bytes);
    float* cpart = lpart + (size_t)MT * Ndim;
    wconv_kernel<<<dim3(Ndim * Kdim / 1024), dim3(256), 0, stream>>>(W, Wb);
    attn_main_fb<<<dim3(MT * NT), dim3(256), 0, stream>>>(X, Wb, bias, lpart, cpart);
    finalize_kernel<<<dim3(Bsz * Hdim / 256), dim3(256), 0, stream>>>(lpart, cpart, out,
                                                                      Sdim / BM);
  }
}

// Round 9
// 250.811 us; speedup vs baseline: 4.7837x; 1.0026x over previous
//
#include <hip/hip_runtime.h>
#include <hip/hip_bf16.h>

// Problem: B=16, S=4096, H=1024
//   energy = tanh(x @ W^T + b); scores = softmax(energy, axis=S); out = sum_S scores*x
// GEMM view: M = B*S = 65536, N = H = 1024, K = H = 1024.
#define Bsz  16
#define Sdim 4096
#define Hdim 1024
#define Mtot (Bsz * Sdim)   // 65536
#define Kdim Hdim
#define Ndim Hdim

// ---- primary tile geometry (256^2, BK=64, 8 waves 2Mx4N, m201 8-phase) ----
#define BM2 256
#define BN2 256
#define MT2 (Mtot / BM2)    // 256
#define NT2 (Ndim / BN2)    // 4
#define NKT64 (Kdim / 64)   // 16 K-tiles
#define NITER (NKT64 / 2)   // 8 iterations of 2 K-tiles

// ---- fallback geometry (R1/R2-proven 128^2) ----
#define BM 128
#define BN 128
#define BK 32
#define MT (Mtot / BM)      // 512
#define NT (Ndim / BN)      // 8
#define NKT (Kdim / BK)     // 32

typedef short s16x8 __attribute__((ext_vector_type(8)));
typedef float f32x4 __attribute__((ext_vector_type(4)));

__device__ __forceinline__ unsigned short f2bf(float f) {
  __hip_bfloat16 h = __float2bfloat16(f);
  unsigned short u;
  __builtin_memcpy(&u, &h, 2);
  return u;
}
__device__ __forceinline__ float bf2f(unsigned short u) {
  __hip_bfloat16 h;
  __builtin_memcpy(&h, &u, 2);
  return __bfloat162float(h);
}
__device__ __forceinline__ s16x8 cvt8(float4 u, float4 v) {
  s16x8 r;
  r[0] = (short)f2bf(u.x); r[1] = (short)f2bf(u.y);
  r[2] = (short)f2bf(u.z); r[3] = (short)f2bf(u.w);
  r[4] = (short)f2bf(v.x); r[5] = (short)f2bf(v.y);
  r[6] = (short)f2bf(v.z); r[7] = (short)f2bf(v.w);
  return r;
}

// async global->LDS, 16B per lane; LDS dest is wave-uniform base + lane*16
__device__ __forceinline__ void gload_lds16(const unsigned short* g, unsigned short* l) {
  __builtin_amdgcn_global_load_lds(
      (const __attribute__((address_space(1))) unsigned int*)g,
      (__attribute__((address_space(3))) unsigned int*)l,
      16, 0, 0);
}

// ---- kernel 0: X fp32 [M][K] -> bf16 Xb (134 MB) ----
__global__ __launch_bounds__(256) void xconv_kernel(const float* __restrict__ X,
                                                    unsigned short* __restrict__ Xb) {
  size_t i = (size_t)blockIdx.x * 256 + threadIdx.x;
  float4 u = reinterpret_cast<const float4*>(X)[2 * i];
  float4 v = reinterpret_cast<const float4*>(X)[2 * i + 1];
  reinterpret_cast<s16x8*>(Xb)[i] = cvt8(u, v);
}

// ---- kernel 1: W fp32 [N][K] -> row-major bf16 Wb (2 MB) ----
__global__ __launch_bounds__(256) void wconv_kernel(const float* __restrict__ W,
                                                    unsigned short* __restrict__ Wb) {
  int i = blockIdx.x * 256 + threadIdx.x;
  float4 v = reinterpret_cast<const float4*>(W)[i];
  ushort4 o;
  o.x = f2bf(v.x); o.y = f2bf(v.y); o.z = f2bf(v.z); o.w = f2bf(v.w);
  reinterpret_cast<ushort4*>(Wb)[i] = o;
}

// =====================================================================
// kernel 2 (primary): 256^2, BK=64, m201-derived 8-phase schedule.
//
// 512 thr = 8 waves (wm=w>>2 in {0,1}, wn=w&3); per-wave out 128x64.
// LDS 128 KB: parity-fixed buffers — even K-tiles in {Aev,Bev}, odd in
// {Aod,Bod}; each = 2 halves x [128 rows][64 k] bf16 (16 KB halves).
//
// Per iter u (K-tiles ta=2u even, tb=2u+1 odd), 8 phases; each phase:
//   { quadrant ds_reads ; stage EXACTLY 1 half-tile (2 gload_lds) ;
//     [vmcnt] ; barrier ; setprio1 ; 16 MFMA ; setprio0 ; barrier }
// Quadrant rota (gray code, B-nh0 cached in regs over ph1->ph4):
//   ph1 (ta,mh0,nh0): read A8+B4   stage Ah1(2u+1)
//   ph2 (ta,mh0,nh1): read B4      stage Bh0(2u+1)
//   ph3 (ta,mh1,nh1): read A8      stage Bh1(2u+1)
//   ph4 (ta,mh1,nh0): cached       stage Ah0(2u+2)   vmcnt(2)
//   ph5..ph8: same for tb, staging Ah1/Bh0/Bh1(2u+2), Ah0(2u+3), vmcnt(2)@ph8
// Overwrite legality: A(ta) fully read after ph3 -> Ah0(2u+2)@ph4 OK, etc.
// vmcnt(2)@ph4 retires Bh1(2u+1)@ph3 and older => tb resident for ph5.
// vmcnt(2)@ph8 retires Bh1(2u+2)@ph7 and older => next ta resident.
// Tail (16 tiles): u=7 stages only ph1-3; ph4 -> vmcnt(0); ph8 -> none.
// NEVER a full drain in steady state (the R5-R8 failure mode).
//
// Swizzle ([128][64] halves, 8 slots/row): phys 16B-slot = s ^ (r&7).
// Inverse pre-applied to gload SOURCE col: s_src = (tid&7)^((tid>>3)&7).
// Read offset elems = r*64 + ((kk*4+lk) ^ (lr&7))*8  (r&7 == lr&7).
// =====================================================================
__global__ __launch_bounds__(512, 2) void attn_main(
    const unsigned short* __restrict__ Xb,  // [Mtot][Kdim] bf16
    const unsigned short* __restrict__ Wb,  // [Ndim][Kdim] bf16
    const float* __restrict__ bias,         // [Ndim]
    float* __restrict__ lpart,              // [MT2][Ndim]
    float* __restrict__ cpart) {            // [MT2][Ndim]
  __shared__ unsigned short Aev[2 * 8192];  // [half][128*64] 32 KB
  __shared__ unsigned short Aod[2 * 8192];  // 32 KB
  __shared__ unsigned short Bev[2 * 8192];  // 32 KB
  __shared__ unsigned short Bod[2 * 8192];  // 32 KB
  __shared__ float red[2][2][BN2];          // 4 KB

  // XCD-chunked bijective swizzle (nwg=1024, 1024%8==0)
  int bid = blockIdx.x;
  int swz = (bid & 7) * (MT2 * NT2 / 8) + (bid >> 3);
  const int mt = swz >> 2;
  const int nt = swz & 3;
  const int m0 = mt * BM2;
  const int n0 = nt * BN2;

  const int tid = threadIdx.x;
  const int l   = tid & 63;
  const int w   = tid >> 6;
  const int wm  = w >> 2;         // 0..1 (M half == A-half index)
  const int wn  = w & 3;          // 0..3 (N quarter; B-half = wn>>1)
  const int lr  = l & 15;
  const int lk  = l >> 4;

  f32x4 acc[8][4];
#pragma unroll
  for (int i = 0; i < 8; i++)
#pragma unroll
    for (int j = 0; j < 4; j++) acc[i][j] = (f32x4){0.f, 0.f, 0.f, 0.f};

  // swizzled k-offsets for frag reads (elements)
  const int xk0 = ((lk ^ (lr & 7)) << 3);
  const int xk1 = (((4 | lk) ^ (lr & 7)) << 3);

  // wave-local LDS half bases
  const unsigned short* AevW = Aev + wm * 8192;
  const unsigned short* AodW = Aod + wm * 8192;
  const unsigned short* BevW = Bev + (wn >> 1) * 8192;
  const unsigned short* BodW = Bod + (wn >> 1) * 8192;

  // ---- staging sources (inverse-swizzled): unit = 64 rows x 64 cols ----
  const int srowU = tid >> 3;                                // 0..63
  const int scolE = (((tid & 7) ^ ((tid >> 3) & 7)) << 3);   // elements
  const unsigned short* sA0 = Xb + (size_t)(m0 + srowU) * Kdim + scolE;
  const unsigned short* sA1 = Xb + (size_t)(m0 + 128 + srowU) * Kdim + scolE;
  const unsigned short* sB0 = Wb + (size_t)(n0 + srowU) * Kdim + scolE;
  const unsigned short* sB1 = Wb + (size_t)(n0 + 128 + srowU) * Kdim + scolE;

#define STG(arrbase, src, tile) do {                              \
    unsigned short* d_ = (arrbase) + w * 512;                     \
    const unsigned short* g_ = (src) + (size_t)(tile) * 64;       \
    gload_lds16(g_, d_);                                          \
    gload_lds16(g_ + 65536, d_ + 4096);                           \
  } while (0)

#define RD_A(base, MH) do {                                              \
    _Pragma("unroll")                                                    \
    for (int mf = 0; mf < 4; ++mf) {                                     \
      const unsigned short* p_ = (base) + ((MH)*64 + mf*16 + lr) * 64;   \
      af[mf][0] = *(const s16x8*)(p_ + xk0);                             \
      af[mf][1] = *(const s16x8*)(p_ + xk1);                             \
    } } while (0)

#define RD_B(base, NH, BF) do {                                          \
    _Pragma("unroll")                                                    \
    for (int nf = 0; nf < 2; ++nf) {                                     \
      const unsigned short* p_ =                                         \
          (base) + ((wn & 1) * 64 + (NH)*32 + nf*16 + lr) * 64;          \
      BF[nf][0] = *(const s16x8*)(p_ + xk0);                             \
      BF[nf][1] = *(const s16x8*)(p_ + xk1);                             \
    } } while (0)

#define MFMA16(MH, NH, BF) do {                                          \
    __builtin_amdgcn_s_setprio(1);                                       \
    _Pragma("unroll")                                                    \
    for (int kk = 0; kk < 2; ++kk)                                       \
      _Pragma("unroll")                                                  \
      for (int mf = 0; mf < 4; ++mf)                                     \
        _Pragma("unroll")                                                \
        for (int nf = 0; nf < 2; ++nf)                                   \
          acc[(MH)*4 + mf][(NH)*2 + nf] =                                \
              __builtin_amdgcn_mfma_f32_16x16x32_bf16(                   \
                  af[mf][kk], BF[nf][kk], acc[(MH)*4 + mf][(NH)*2 + nf], \
                  0, 0, 0);                                              \
    __builtin_amdgcn_s_setprio(0);                                       \
  } while (0)

#define BAR() do {                                   \
    asm volatile("" ::: "memory");                   \
    __builtin_amdgcn_s_barrier();                    \
    asm volatile("" ::: "memory");                   \
  } while (0)
#define VM2() asm volatile("s_waitcnt vmcnt(2)" ::: "memory")
#define VM0() asm volatile("s_waitcnt vmcnt(0)" ::: "memory")

  // ---- prologue: tile0 fully + Ah0(tile1); land tile0 ----
  STG(Aev + 0,    sA0, 0);
  STG(Aev + 8192, sA1, 0);
  STG(Bev + 0,    sB0, 0);
  STG(Bev + 8192, sB1, 0);
  STG(Aod + 0,    sA0, 1);
  VM2();                      // 10 issued; retire first 8 = tile0
  BAR();

  for (int u = 0; u < NITER; ++u) {
    const int t1o = 2 * u + 1;          // this iter's odd tile (tb)
    const int t2  = 2 * u + 2;          // next even tile
    const int t3  = 2 * u + 3;          // next odd tile
    const bool st = (u < NITER - 1);    // stage-next enable
    s16x8 af[4][2], bf0[2][2], bf1[2][2];

    // ph1 (ta, mh0, nh0)
    RD_A(AevW, 0); RD_B(BevW, 0, bf0);
    STG(Aod + 8192, sA1, t1o);
    BAR(); MFMA16(0, 0, bf0); BAR();

    // ph2 (ta, mh0, nh1)
    RD_B(BevW, 1, bf1);
    STG(Bod + 0, sB0, t1o);
    BAR(); MFMA16(0, 1, bf1); BAR();

    // ph3 (ta, mh1, nh1)
    RD_A(AevW, 1);
    STG(Bod + 8192, sB1, t1o);
    BAR(); MFMA16(1, 1, bf1); BAR();

    // ph4 (ta, mh1, nh0) — bf0 cached
    if (st) STG(Aev + 0, sA0, t2);
    if (st) VM2(); else VM0();          // tb fully resident
    BAR(); MFMA16(1, 0, bf0); BAR();

    // ph5 (tb, mh0, nh0)
    RD_A(AodW, 0); RD_B(BodW, 0, bf0);
    if (st) STG(Aev + 8192, sA1, t2);
    BAR(); MFMA16(0, 0, bf0); BAR();

    // ph6 (tb, mh0, nh1)
    RD_B(BodW, 1, bf1);
    if (st) STG(Bev + 0, sB0, t2);
    BAR(); MFMA16(0, 1, bf1); BAR();

    // ph7 (tb, mh1, nh1)
    RD_A(AodW, 1);
    if (st) STG(Bev + 8192, sB1, t2);
    BAR(); MFMA16(1, 1, bf1); BAR();

    // ph8 (tb, mh1, nh0) — bf0 cached
    if (st) STG(Aod + 0, sA0, t3);
    if (st) VM2();                      // next ta fully resident
    BAR(); MFMA16(1, 0, bf0); BAR();
  }

  // ---- epilogue: e = tanh(acc+bias); l = sum exp(e), c = sum exp(e)*x ----
  // C/D layout: col = lane&15, row = (lane>>4)*4 + reg.
  // acc[m8] rows: wm*128 + (m8>>2)*64 + (m8&3)*16. tanh bounded -> no max sub.
  float lsum[4], csum[4];
#pragma unroll
  for (int nr = 0; nr < 4; nr++) {
    const int o = n0 + wn * 64 + nr * 16 + lr;
    const float bv = bias[o];
    float lacc = 0.f, cacc = 0.f;
#pragma unroll
    for (int m8 = 0; m8 < 8; m8++) {
      const int sr = m0 + wm * 128 + (m8 >> 2) * 64 + (m8 & 3) * 16 + lk * 4;
#pragma unroll
      for (int r = 0; r < 4; r++) {
        float e  = acc[m8][nr][r] + bv;
        float t  = __expf(2.f * e);
        float th = 1.f - __fdividef(2.f, t + 1.f);  // tanh(e); e bounded ~[-7,7]
        float sc = __expf(th);                      // in [0.37, 2.72]
        float xv = bf2f(Xb[(size_t)(sr + r) * Kdim + o]);  // L2-warm
        lacc += sc;
        cacc += sc * xv;
      }
    }
    lacc += __shfl_xor(lacc, 16); lacc += __shfl_xor(lacc, 32);
    cacc += __shfl_xor(cacc, 16); cacc += __shfl_xor(cacc, 32);
    lsum[nr] = lacc; csum[nr] = cacc;
  }

  if (lk == 0) {
#pragma unroll
    for (int nr = 0; nr < 4; nr++) {
      red[wm][0][wn * 64 + nr * 16 + lr] = lsum[nr];
      red[wm][1][wn * 64 + nr * 16 + lr] = csum[nr];
    }
  }
  __syncthreads();
  if (tid < BN2) {
    float L = red[0][0][tid] + red[1][0][tid];
    float C = red[0][1][tid] + red[1][1][tid];
    lpart[(size_t)mt * Ndim + n0 + tid] = L;
    cpart[(size_t)mt * Ndim + n0 + tid] = C;
  }
}

// ---- fallback main (R2-proven 128^2 reg-staged path, if ws too small) ----
__global__ __launch_bounds__(256) void attn_main_fb(
    const float* __restrict__ X, const unsigned short* __restrict__ Wb,
    const float* __restrict__ bias, float* __restrict__ lpart, float* __restrict__ cpart) {
  __shared__ unsigned short Al[BM * BK];
  __shared__ unsigned short Bl[BN * BK];
  __shared__ float red[2][2][BN];
  int bid = blockIdx.x;
  int swz = (bid & 7) * (MT * NT / 8) + (bid >> 3);
  int mt = swz >> 3, nt = swz & 7;
  const int m0 = mt * BM, n0 = nt * BN;
  const int tid = threadIdx.x, lane = tid & 63, wave = tid >> 6;
  const int wm = wave >> 1, wn = wave & 1, lr = lane & 15, lk = lane >> 4;
  f32x4 acc[4][4];
#pragma unroll
  for (int i = 0; i < 4; i++)
#pragma unroll
    for (int j = 0; j < 4; j++) acc[i][j] = (f32x4){0.f, 0.f, 0.f, 0.f};
  const int srow_st = tid >> 1, scol_st = (tid & 1) * 16;
  const float*          Ag = X  + (size_t)(m0 + srow_st) * Kdim + scol_st;
  const unsigned short* Bg = Wb + (size_t)(n0 + srow_st) * Kdim + scol_st;
  float4 a0 = *(const float4*)(Ag + 0), a1 = *(const float4*)(Ag + 4);
  float4 a2 = *(const float4*)(Ag + 8), a3 = *(const float4*)(Ag + 12);
  s16x8 b0 = *(const s16x8*)(Bg + 0), b1 = *(const s16x8*)(Bg + 8);
  for (int kt = 0; kt < NKT; ++kt) {
    __syncthreads();
    *(s16x8*)&Al[srow_st * BK + scol_st]     = cvt8(a0, a1);
    *(s16x8*)&Al[srow_st * BK + scol_st + 8] = cvt8(a2, a3);
    *(s16x8*)&Bl[srow_st * BK + scol_st]     = b0;
    *(s16x8*)&Bl[srow_st * BK + scol_st + 8] = b1;
    __syncthreads();
    if (kt + 1 < NKT) {
      const float* ap = Ag + (kt + 1) * BK;
      a0 = *(const float4*)(ap);     a1 = *(const float4*)(ap + 4);
      a2 = *(const float4*)(ap + 8); a3 = *(const float4*)(ap + 12);
      const unsigned short* bp = Bg + (kt + 1) * BK;
      b0 = *(const s16x8*)(bp);      b1 = *(const s16x8*)(bp + 8);
    }
    s16x8 af[4], bfr[4];
#pragma unroll
    for (int mr = 0; mr < 4; mr++)
      af[mr] = *(const s16x8*)&Al[(wm * 64 + mr * 16 + lr) * BK + lk * 8];
#pragma unroll
    for (int nr = 0; nr < 4; nr++)
      bfr[nr] = *(const s16x8*)&Bl[(wn * 64 + nr * 16 + lr) * BK + lk * 8];
#pragma unroll
    for (int mr = 0; mr < 4; mr++)
#pragma unroll
      for (int nr = 0; nr < 4; nr++)
        acc[mr][nr] = __builtin_amdgcn_mfma_f32_16x16x32_bf16(af[mr], bfr[nr], acc[mr][nr], 0, 0, 0);
  }
  float lsum[4], csum[4];
#pragma unroll
  for (int nr = 0; nr < 4; nr++) {
    const int o = n0 + wn * 64 + nr * 16 + lr;
    const float bv = bias[o];
    float lacc = 0.f, cacc = 0.f;
#pragma unroll
    for (int mr = 0; mr < 4; mr++) {
      const int sr = m0 + wm * 64 + mr * 16 + lk * 4;
#pragma unroll
      for (int r = 0; r < 4; r++) {
        float e  = acc[mr][nr][r] + bv;
        float t  = __expf(2.f * e);
        float th = 1.f - __fdividef(2.f, t + 1.f);
        float sc = __expf(th);
        float xv = X[(size_t)(sr + r) * Kdim + o];
        lacc += sc; cacc += sc * xv;
      }
    }
    lacc += __shfl_xor(lacc, 16); lacc += __shfl_xor(lacc, 32);
    cacc += __shfl_xor(cacc, 16); cacc += __shfl_xor(cacc, 32);
    lsum[nr] = lacc; csum[nr] = cacc;
  }
  if (lk == 0) {
#pragma unroll
    for (int nr = 0; nr < 4; nr++) {
      red[wm][0][wn * 64 + nr * 16 + lr] = lsum[nr];
      red[wm][1][wn * 64 + nr * 16 + lr] = csum[nr];
    }
  }
  __syncthreads();
  if (tid < BN) {
    float L = red[0][0][tid] + red[1][0][tid];
    float C = red[0][1][tid] + red[1][1][tid];
    lpart[(size_t)mt * Ndim + n0 + tid] = L;
    cpart[(size_t)mt * Ndim + n0 + tid] = C;
  }
}

// ---- kernel 3: combine s-chunks -> out[b][o] ----
__global__ __launch_bounds__(256) void finalize_kernel(const float* __restrict__ lpart,
                                                       const float* __restrict__ cpart,
                                                       float* __restrict__ out, int chunks) {
  int i = blockIdx.x * 256 + threadIdx.x;
  int b = i >> 10, o = i & 1023;
  float L = 0.f, C = 0.f;
  for (int sc = 0; sc < chunks; ++sc) {
    size_t idx = (size_t)(b * chunks + sc) * Ndim + o;
    L += lpart[idx];
    C += cpart[idx];
  }
  out[i] = C / L;
}

extern "C" void kernel_launch(void* const* d_in, const int* in_sizes, int n_in,
                              void* d_out, int out_size, void* d_ws, size_t ws_size,
                              hipStream_t stream) {
  const float* X    = (const float*)d_in[0];
  const float* W    = (const float*)d_in[1];
  const float* bias = (const float*)d_in[2];
  float* out = (float*)d_out;

  const size_t xb_bytes = (size_t)Mtot * Kdim * 2;        // 134 MB
  const size_t wb_bytes = (size_t)Ndim * Kdim * 2;        // 2 MB
  const size_t lp_bytes = (size_t)MT * Ndim * 4;          // 2 MB
  const size_t need = xb_bytes + wb_bytes + 2 * lp_bytes;

  if (ws_size >= need) {
    unsigned short* Xb = (unsigned short*)d_ws;
    unsigned short* Wb = (unsigned short*)((char*)d_ws + xb_bytes);
    float* lpart = (float*)((char*)d_ws + xb_bytes + wb_bytes);
    float* cpart = lpart + (size_t)MT2 * Ndim;
    xconv_kernel<<<dim3(Mtot * (Kdim / 8) / 256), dim3(256), 0, stream>>>(X, Xb);
    wconv_kernel<<<dim3(Ndim * Kdim / 1024), dim3(256), 0, stream>>>(W, Wb);
    attn_main<<<dim3(MT2 * NT2), dim3(512), 0, stream>>>(Xb, Wb, bias, lpart, cpart);
    finalize_kernel<<<dim3(Bsz * Hdim / 256), dim3(256), 0, stream>>>(lpart, cpart, out,
                                                                      Sdim / BM2);
  } else {
    unsigned short* Wb = (unsigned short*)d_ws;
    float* lpart = (float*)((char*)d_ws + wb_bytes);
    float* cpart = lpart + (size_t)MT * Ndim;
    wconv_kernel<<<dim3(Ndim * Kdim / 1024), dim3(256), 0, stream>>>(W, Wb);
    attn_main_fb<<<dim3(MT * NT), dim3(256), 0, stream>>>(X, Wb, bias, lpart, cpart);
    finalize_kernel<<<dim3(Bsz * Hdim / 256), dim3(256), 0, stream>>>(lpart, cpart, out,
                                                                      Sdim / BM);
  }
}